// Round 7
// baseline (88.397 us; speedup 1.0000x reference)
//
#include <hip/hip_runtime.h>

// SparseProductLayer:  out = x @ (M0*M1*M2)^T + bias
// Pipeline: multi-block CSR build -> entry-wise Mc build -> x->bf16 ->
// reg-pipelined MFMA GEMM: BM=128,BN=256,BK=32, 4-slot LDS ring (96 KB),
// stage 3 steps ahead, ds_reads for step s+1 issued before step s's MFMA,
// counted vmcnt(3), one barrier/K-step, involution LDS swizzle, setprio.
// 256 blocks = 1/CU.
//
// d_ws layout (bytes):
//   [0)         Mc  bf16 [D][D]     8388608
//   [8388608)   Xb  bf16 [B][D]    16777216
//   [25165824)  CSR: off[3][2052], cur[3][2048], col[3][16384], val[3][16384]

#define BATCH 4096
#define DIM   2048
#define NNZc  16384
#define NT    256

typedef short bf16x8 __attribute__((ext_vector_type(8)));
typedef float f32x4  __attribute__((ext_vector_type(4)));

__device__ __forceinline__ unsigned short f2bf(float f) {
    unsigned u = __float_as_uint(f);
    unsigned r = (u + 0x7fffu + ((u >> 16) & 1u)) >> 16;   // RNE
    return (unsigned short)r;
}

__device__ __forceinline__ void gload16(const void* g, void* l) {
    __builtin_amdgcn_global_load_lds((const __attribute__((address_space(1))) void*)g,
                                     (__attribute__((address_space(3))) void*)l, 16, 0, 0);
}

// ---- CSR build: histogram (all 3 matrices, multi-block) ----
__global__ void hist_kernel(const int* __restrict__ rows0, const int* __restrict__ rows1,
                            const int* __restrict__ rows2, int* __restrict__ cur) {
    int e = blockIdx.x * NT + threadIdx.x;          // 0 .. 3*NNZ
    int m = e >> 14, i = e & (NNZc - 1);
    const int* rp = (m == 0) ? rows0 : (m == 1) ? rows1 : rows2;
    atomicAdd(&cur[m * DIM + rp[i]], 1);
}

// ---- CSR build: exclusive scan of 2048 counts (one block per matrix) ----
__global__ void scan_kernel(int* __restrict__ curb, int* __restrict__ offb) {
    int* cur = curb + blockIdx.x * DIM;
    int* off = offb + blockIdx.x * 2052;
    __shared__ int part[NT];
    int t = threadIdx.x;
    int c[8]; int s = 0;
    #pragma unroll
    for (int i = 0; i < 8; ++i) { c[i] = cur[t * 8 + i]; s += c[i]; }
    part[t] = s;
    __syncthreads();
    if (t == 0) {
        int run = 0;
        for (int i = 0; i < NT; ++i) { int v = part[i]; part[i] = run; run += v; }
    }
    __syncthreads();
    int base = part[t];
    #pragma unroll
    for (int i = 0; i < 8; ++i) {
        int idx = t * 8 + i;
        off[idx] = base; cur[idx] = base; base += c[i];
    }
    if (t == 0) off[DIM] = NNZc;
}

// ---- CSR build: scatter entries into row buckets ----
__global__ void scatter_kernel(const int* __restrict__ rows0, const int* __restrict__ cols0,
                               const float* __restrict__ vals0,
                               const int* __restrict__ rows1, const int* __restrict__ cols1,
                               const float* __restrict__ vals1,
                               const int* __restrict__ rows2, const int* __restrict__ cols2,
                               const float* __restrict__ vals2,
                               int* __restrict__ cur,
                               int* __restrict__ colb, float* __restrict__ valb) {
    int e = blockIdx.x * NT + threadIdx.x;
    int m = e >> 14, i = e & (NNZc - 1);
    const int*   rp = (m == 0) ? rows0 : (m == 1) ? rows1 : rows2;
    const int*   cp = (m == 0) ? cols0 : (m == 1) ? cols1 : cols2;
    const float* vp = (m == 0) ? vals0 : (m == 1) ? vals1 : vals2;
    int slot = atomicAdd(&cur[m * DIM + rp[i]], 1);
    colb[m * NNZc + slot] = cp[i];
    valb[m * NNZc + slot] = vp[i];
}

// ---- Mc build: per block, RPB output rows via 3-level tree walk in LDS ----
#define RPB  2
#define PCAP 2048
__global__ __launch_bounds__(NT) void mcbuild_kernel(
        const int* __restrict__ offb, const int* __restrict__ colb,
        const float* __restrict__ valb, unsigned short* __restrict__ Mc) {
    const int* off0 = offb;              const int* off1 = offb + 2052;  const int* off2 = offb + 4104;
    const int* col0 = colb;              const int* col1 = colb + NNZc;  const int* col2 = colb + 2 * NNZc;
    const float* val0 = valb;            const float* val1 = valb + NNZc; const float* val2 = valb + 2 * NNZc;

    __shared__ float acc[RPB * DIM];
    __shared__ int   pk[PCAP];
    __shared__ float pw[PCAP];
    __shared__ int   npairs;

    const int tid = threadIdx.x;
    const int r0  = blockIdx.x * RPB;

    f32x4* az = (f32x4*)acc;
    #pragma unroll
    for (int j = tid; j < RPB * DIM / 4; j += NT) az[j] = (f32x4){0.f, 0.f, 0.f, 0.f};
    if (tid == 0) npairs = 0;
    __syncthreads();

    #pragma unroll
    for (int k = 0; k < RPB; ++k) {
        int b = off0[r0 + k], e = off0[r0 + k + 1];
        for (int i = b + tid; i < e; i += NT) {
            int   c0 = col0[i];
            float v0 = val0[i];
            int b1 = off1[c0], e1 = off1[c0 + 1];
            for (int j = b1; j < e1; ++j) {
                float w = v0 * val1[j];
                int   c1 = col1[j];
                int slot = atomicAdd(&npairs, 1);
                if (slot < PCAP) { pk[slot] = (k << 16) | c1; pw[slot] = w; }
                else {
                    int b2 = off2[c1], e2 = off2[c1 + 1];
                    for (int q = b2; q < e2; ++q)
                        atomicAdd(&acc[k * DIM + col2[q]], w * val2[q]);
                }
            }
        }
    }
    __syncthreads();

    int np = min(npairs, PCAP);
    for (int p = tid; p < np; p += NT) {
        int   k  = pk[p] >> 16, c1 = pk[p] & 0xffff;
        float w  = pw[p];
        int b2 = off2[c1], e2 = off2[c1 + 1];
        for (int q = b2; q < e2; ++q)
            atomicAdd(&acc[k * DIM + col2[q]], w * val2[q]);
    }
    __syncthreads();

    #pragma unroll
    for (int k = 0; k < RPB; ++k) {
        unsigned short o[8];
        #pragma unroll
        for (int jj = 0; jj < 8; ++jj) o[jj] = f2bf(acc[k * DIM + tid * 8 + jj]);
        *(ulonglong2*)(Mc + (size_t)(r0 + k) * DIM + tid * 8) = *(ulonglong2*)o;
    }
}

// ---- x (f32) -> bf16 ----
__global__ void xconv_kernel(const float* __restrict__ x, unsigned short* __restrict__ Xb) {
    size_t i = ((size_t)blockIdx.x * NT + threadIdx.x) * 8;
    float4 a = *(const float4*)(x + i);
    float4 b = *(const float4*)(x + i + 4);
    unsigned short o[8] = {f2bf(a.x), f2bf(a.y), f2bf(a.z), f2bf(a.w),
                           f2bf(b.x), f2bf(b.y), f2bf(b.z), f2bf(b.w)};
    *(ulonglong2*)(Xb + i) = *(ulonglong2*)o;
}

// ---- GEMM: C = Xb(4096x2048) @ Mc^T + bias ----
// Register-pipelined: ds_reads for step s+1 issued before step s's MFMA;
// 4-slot LDS ring staged 3 ahead; vmcnt(3) after MFMA; one barrier/step.
// LDS layout per slot: A [128 rows][32 cols] bf16 (64 B rows), B [256][32].
// Involution swizzle: phys_chunk = log_chunk ^ ((row>>1)&3)  (16B chunks).
#define BM 128
#define BN 256
#define BK 32
#define NS (DIM / BK)            // 64
#define A_SL (BM * BK * 2)       // 8192
#define B_SL (BN * BK * 2)       // 16384
#define SLOT (A_SL + B_SL)       // 24576
#define GEMM_LDS (4 * SLOT)      // 98304

__global__ __launch_bounds__(512, 2) void gemm8(
        const unsigned short* __restrict__ A,   // Xb [4096][2048]
        const unsigned short* __restrict__ Bm,  // Mc [2048][2048]
        const float* __restrict__ bias,
        float* __restrict__ C) {
    extern __shared__ char smem[];
    const int tid = threadIdx.x;
    const int l = tid & 63, w = tid >> 6;
    const int wm = w & 1, wn = w >> 1;          // 2 x 4 wave grid, wave tile 64x64
    const int tileM = blockIdx.y * BM;
    const int tileN = blockIdx.x * BN;

    // ---- staging: thread (w,l) covers row lr, 16B chunk (l&3); source pre-swizzled ----
    const int lr = l >> 2;                          // 0..15
    const int lc = (l & 3) ^ ((l >> 3) & 3);        // logical chunk for phys chunk l&3
    const unsigned short* aSrc  = A  + (size_t)(tileM + 16 * w + lr) * DIM + lc * 8;
    const unsigned short* bSrc0 = Bm + (size_t)(tileN + 32 * w + lr) * DIM + lc * 8;
    const unsigned short* bSrc1 = bSrc0 + (size_t)16 * DIM;

#define STAGE(zbase, s) do {                                              \
    gload16(aSrc  + (size_t)(s) * BK, (zbase) + w * 1024);                \
    gload16(bSrc0 + (size_t)(s) * BK, (zbase) + A_SL + w * 2048);         \
    gload16(bSrc1 + (size_t)(s) * BK, (zbase) + A_SL + w * 2048 + 1024);  \
} while (0)

    // ---- frag reads: lane row = (l&15), logical k-chunk = l>>4, swizzled ----
    const int sw   = (((l >> 4) ^ ((l >> 1) & 3)) * 16);
    const int arow = (wm * 64 + (l & 15)) * 64 + sw;     // + q*1024
    const int brow = (wn * 64 + (l & 15)) * 64 + sw;     // + j*1024 (within B region)

#define LOADFRAGS(zbase, Af, Bf) do {                    \
    const char* _ab = (zbase) + arow;                    \
    Af[0] = *(const bf16x8*)(_ab);                       \
    Af[1] = *(const bf16x8*)(_ab + 1024);                \
    Af[2] = *(const bf16x8*)(_ab + 2048);                \
    Af[3] = *(const bf16x8*)(_ab + 3072);                \
    const char* _bb = (zbase) + A_SL + brow;             \
    Bf[0] = *(const bf16x8*)(_bb);                       \
    Bf[1] = *(const bf16x8*)(_bb + 1024);                \
    Bf[2] = *(const bf16x8*)(_bb + 2048);                \
    Bf[3] = *(const bf16x8*)(_bb + 3072);                \
} while (0)

#define MFMA16(Af, Bf) do {                                                            \
    _Pragma("unroll")                                                                  \
    for (int _q = 0; _q < 4; ++_q)                                                     \
        _Pragma("unroll")                                                              \
        for (int _j = 0; _j < 4; ++_j)                                                 \
            acc[_q][_j] = __builtin_amdgcn_mfma_f32_16x16x32_bf16(Af[_q], Bf[_j],      \
                                                                  acc[_q][_j], 0,0,0); \
} while (0)

#define WAITS_BAR(vm) do {                                    \
    __builtin_amdgcn_sched_barrier(0);                        \
    asm volatile("s_waitcnt vmcnt(" #vm ")" ::: "memory");    \
    asm volatile("s_waitcnt lgkmcnt(0)" ::: "memory");        \
    __builtin_amdgcn_sched_barrier(0);                        \
    __builtin_amdgcn_s_barrier();                             \
} while (0)

    bf16x8 Ae[4], Be[4], Ao[4], Bo[4];
    f32x4 acc[4][4] = {};

    // ---- prologue: stage steps 0..2; load step0 frags ----
    STAGE(smem, 0);
    asm volatile("s_waitcnt vmcnt(0)" ::: "memory");
    __builtin_amdgcn_s_barrier();
    STAGE(smem + 1 * SLOT, 1);
    STAGE(smem + 2 * SLOT, 2);
    LOADFRAGS(smem, Ae, Be);
    WAITS_BAR(3);   // step1 staged + step0 frags in regs

    // ---- main loop: pairs of steps; even computes Ae/Be, odd Ao/Bo ----
    for (int t = 0; t < 30; ++t) {
        const int s = 2 * t;
        {   // even body: compute s, load s+1, stage s+3
            STAGE(smem + ((s + 3) & 3) * SLOT, s + 3);
            LOADFRAGS(smem + ((s + 1) & 3) * SLOT, Ao, Bo);
            __builtin_amdgcn_sched_barrier(0);
            __builtin_amdgcn_s_setprio(1);
            MFMA16(Ae, Be);
            __builtin_amdgcn_s_setprio(0);
            WAITS_BAR(3);
        }
        {   // odd body: compute s+1, load s+2, stage s+4
            STAGE(smem + ((s + 4) & 3) * SLOT, s + 4);
            LOADFRAGS(smem + ((s + 2) & 3) * SLOT, Ae, Be);
            __builtin_amdgcn_sched_barrier(0);
            __builtin_amdgcn_s_setprio(1);
            MFMA16(Ao, Bo);
            __builtin_amdgcn_s_setprio(0);
            WAITS_BAR(3);
        }
    }
    // ---- tail: steps 60..63 ----
    {   // s=60: stage 63, load 61, compute 60
        STAGE(smem + 3 * SLOT, 63);
        LOADFRAGS(smem + 1 * SLOT, Ao, Bo);
        __builtin_amdgcn_sched_barrier(0);
        __builtin_amdgcn_s_setprio(1);
        MFMA16(Ae, Be);
        __builtin_amdgcn_s_setprio(0);
        WAITS_BAR(3);   // drains step-62 staging
    }
    {   // s=61: load 62, compute 61
        LOADFRAGS(smem + 2 * SLOT, Ae, Be);
        __builtin_amdgcn_sched_barrier(0);
        __builtin_amdgcn_s_setprio(1);
        MFMA16(Ao, Bo);
        __builtin_amdgcn_s_setprio(0);
        WAITS_BAR(0);   // drains step-63 staging
    }
    {   // s=62: load 63, compute 62
        LOADFRAGS(smem + 3 * SLOT, Ao, Bo);
        __builtin_amdgcn_sched_barrier(0);
        __builtin_amdgcn_s_setprio(1);
        MFMA16(Ae, Be);
        __builtin_amdgcn_s_setprio(0);
        __builtin_amdgcn_sched_barrier(0);
        asm volatile("s_waitcnt lgkmcnt(0)" ::: "memory");
        __builtin_amdgcn_sched_barrier(0);
    }
    // s=63
    MFMA16(Ao, Bo);

    // ---- epilogue: C = acc + bias ----
    #pragma unroll
    for (int j = 0; j < 4; ++j) {
        int col = tileN + wn * 64 + j * 16 + (l & 15);
        float bj = bias[col];
        #pragma unroll
        for (int i = 0; i < 4; ++i) {
            int rw = tileM + wm * 64 + i * 16 + (l >> 4) * 4;
            #pragma unroll
            for (int r = 0; r < 4; ++r)
                C[(size_t)(rw + r) * DIM + col] = acc[i][j][r] + bj;
        }
    }
}

extern "C" void kernel_launch(void* const* d_in, const int* in_sizes, int n_in,
                              void* d_out, int out_size, void* d_ws, size_t ws_size,
                              hipStream_t stream) {
    const float* x     = (const float*)d_in[0];
    const int*   rows0 = (const int*)  d_in[1];
    const int*   cols0 = (const int*)  d_in[2];
    const float* vals0 = (const float*)d_in[3];
    const int*   rows1 = (const int*)  d_in[4];
    const int*   cols1 = (const int*)  d_in[5];
    const float* vals1 = (const float*)d_in[6];
    const int*   rows2 = (const int*)  d_in[7];
    const int*   cols2 = (const int*)  d_in[8];
    const float* vals2 = (const float*)d_in[9];
    const float* bias  = (const float*)d_in[10];
    float* out = (float*)d_out;

    char* ws = (char*)d_ws;
    unsigned short* Mc = (unsigned short*)ws;                 // 8 MB
    unsigned short* Xb = (unsigned short*)(ws + 8388608);     // 16 MB
    int*   offb = (int*)(ws + 25165824);      // 3 * 2052
    int*   curb = offb + 3 * 2052;            // 3 * 2048
    int*   colb = curb + 3 * DIM;             // 3 * 16384
    float* valb = (float*)(colb + 3 * NNZc);  // 3 * 16384

    hipMemsetAsync(curb, 0, 3 * DIM * sizeof(int), stream);

    hist_kernel<<<3 * NNZc / NT, NT, 0, stream>>>(rows0, rows1, rows2, curb);
    scan_kernel<<<3, NT, 0, stream>>>(curb, offb);
    scatter_kernel<<<3 * NNZc / NT, NT, 0, stream>>>(rows0, cols0, vals0,
                                                     rows1, cols1, vals1,
                                                     rows2, cols2, vals2,
                                                     curb, colb, valb);
    mcbuild_kernel<<<DIM / RPB, NT, 0, stream>>>(offb, colb, valb, Mc);
    xconv_kernel<<<(BATCH * DIM) / (NT * 8), NT, 0, stream>>>(x, Xb);

    (void)hipFuncSetAttribute((const void*)gemm8,
                              hipFuncAttributeMaxDynamicSharedMemorySize, GEMM_LDS);
    dim3 ggrid(DIM / BN, BATCH / BM);   // 8 x 32 = 256 blocks
    gemm8<<<ggrid, 512, GEMM_LDS, stream>>>(Xb, Mc, bias, out);
}